// Round 6
// baseline (177.239 us; speedup 1.0000x reference)
//
#include <hip/hip_runtime.h>
#include <cstdint>
#include <cmath>

#define B_ 4
#define H_ 256
#define C_ 80
#define TX_ 256
#define TY_ 1024
#define NEGF (-1e9f)

// output layout (floats): o_en_ex [B,H,TY] | logp [B,TX,TY] | attn [B,TX,TY] | dr [B,TX]
#define OFF_LOGP (B_*H_*TY_)
#define OFF_ATTN (OFF_LOGP + B_*TX_*TY_)
#define OFF_DR   (OFF_ATTN + B_*TX_*TY_)

// __shfl_up(x,1) as pure VALU: DPP wave_shr:1 (ctrl 0x138); lane 0 gets NEGF.
__device__ __forceinline__ float dpp_shr1_negfill_f32(float x) {
  union { float f; int i; } u, o, r;
  u.f = x; o.f = NEGF;
  r.i = __builtin_amdgcn_update_dpp(o.i, u.i, 0x138, 0xf, 0xf, false);
  return r.f;
}

// ---------------------------------------------------------------------------
// Kernel A (R19): logp at 8 blocks/CU; math BIT-IDENTICAL to R18/R3.
//
// R18 post-mortem: 4 waves/SIMD recovered only ~13us of the modeled ~60 ->
// still latency-exposed (or overhead-bound).  This round: tq split x8
// (128 t's per block, 2 t's per lane, float2 y loads), grid (64,8,4)=2048
// blocks = 8 blocks/CU = 8 waves/SIMD; prologue mu/ls loads vectorized as
// float4 over x.  Per-element FMA chain and c-order unchanged -> logp/lpT
// bit-identical (absmax stays 0.0078125; DP tie-breaks cannot flip).
// LDS ~12.4KB.
// ---------------------------------------------------------------------------
__global__ __launch_bounds__(256) void k_logp(
    const float* __restrict__ mu, const float* __restrict__ ls,
    const float* __restrict__ y, const int* __restrict__ xlp,
    const int* __restrict__ ylp, float* __restrict__ logp_out,
    float* __restrict__ lpT)
{
  const int b  = blockIdx.z;
  const int tq = blockIdx.y;              // t-eighth: rows tq*128 .. tq*128+127
  const int x0 = blockIdx.x * 4;
  const int tid = threadIdx.x;
  const int lane = tid & 63;
  const int xi = tid >> 6;                // wave id == x-column index

  __shared__ double2 s_wm[4][C_];         // (w, -2*w*mu) packed -> ds_read_b128
  __shared__ double  s_wm2[4][C_];
  __shared__ double  s_lsv[4][C_];
  __shared__ double  s_K[4];
  __shared__ double  s_t0[4];
  __shared__ float   tile[128][4];        // [t_local][x] transpose staging

  for (int c = tid; c < C_; c += 256) {
    float4 m4 = *(const float4*)&mu[(b * C_ + c) * TX_ + x0];
    float4 l4 = *(const float4*)&ls[(b * C_ + c) * TX_ + x0];
    const float mv[4] = {m4.x, m4.y, m4.z, m4.w};
    const float lv[4] = {l4.x, l4.y, l4.z, l4.w};
#pragma unroll
    for (int xj = 0; xj < 4; ++xj) {
      double m = (double)mv[xj];
      double l = (double)lv[xj];
      double w = exp(-2.0 * l);
      s_wm[xj][c]  = make_double2(w, -2.0 * w * m);
      s_wm2[xj][c] = w * m * m;
      s_lsv[xj][c] = l;
    }
  }
  __syncthreads();
  {
    int cc = lane;
    double kp = (cc < C_) ? s_wm2[xi][cc] : 0.0;
    double tp = (cc < C_) ? s_lsv[xi][cc] : 0.0;
    if (cc + 64 < C_) { kp += s_wm2[xi][cc + 64]; tp += s_lsv[xi][cc + 64]; }
#pragma unroll
    for (int off = 32; off; off >>= 1) {
      kp += __shfl_down(kp, off);
      tp += __shfl_down(tp, off);
    }
    if (cc == 0) { s_K[xi] = kp; s_t0[xi] = -0.5 * (tp * (1.0 / C_)); }
  }
  __syncthreads();

  // each thread: x = x0+xi, t = tq*128 + lane*2, lane*2+1
  double acc0 = 0.0, acc1 = 0.0;
  const float2* yp = (const float2*)(y + (size_t)b * C_ * TY_ + tq * 128) + lane;
#pragma unroll 4
  for (int c = 0; c < C_; ++c) {
    float2 yv = yp[c * (TY_ / 2)];
    double y0 = yv.x, y1 = yv.y;
    double2 wm = s_wm[xi][c];
    double w = wm.x, m1 = wm.y;
    double u0 = fma(w, y0, m1), u1 = fma(w, y1, m1);
    acc0 = fma(u0, y0, acc0);
    acc1 = fma(u1, y1, acc1);
  }

  const int xlen = xlp[b], ylen = ylp[b];
  const int x  = x0 + xi;
  const int t0 = tq * 128 + lane * 2;
  {
    double c0 = s_t0[xi], K = s_K[xi];
    float r0 = (float)((acc0 + K) * (-0.5 / C_) + c0);
    float r1 = (float)((acc1 + K) * (-0.5 / C_) + c0);
    *(float2*)&logp_out[((size_t)(b * TX_ + x)) * TY_ + t0] = make_float2(r0, r1);
    bool xm = x < xlen;
    tile[lane * 2    ][xi] = (xm && (t0    ) < ylen) ? r0 : NEGF;
    tile[lane * 2 + 1][xi] = (xm && (t0 + 1) < ylen) ? r1 : NEGF;
  }
  __syncthreads();

  // lpT[b][t][x0..x0+3] for t in this eighth; threads 0..127 store one row
  if (tid < 128) {
    float* dst = lpT + (size_t)b * TY_ * TX_ + x0;
    *(float4*)&dst[(size_t)(tq * 128 + tid) * TX_] = ((const float4*)tile)[tid];
  }
}

// ---------------------------------------------------------------------------
// Kernel B (R19): barrier-free producer-consumer Viterbi DP (R16 forward,
// validated 79.6us) + STRIP-CACHED backtrack.
//
// Backtrack model: 256 serial iterations, each gated by a dependent
// ds_read_b32 (~120cyc) -> ~36k cyc, roughly half of k_dp.  bits[ww*256+idx]
// is contiguous in idx and idx decrements by exactly 1 per iteration, so a
// uint4 strip caches 4 columns per load: reload only when idx crosses a
// 4-boundary or ww changes (~95 loads vs 256).  Word values consumed are
// bit-identical to the reference walk -> identical dur[].
// ---------------------------------------------------------------------------
#define POLL_FLAG(i)                                                     \
  { while (vflag[i] == 0u) __builtin_amdgcn_s_sleep(1);                  \
    asm volatile("" ::: "memory"); }

#define DP_CHUNK(SHBASE)                                                 \
  _Pragma("unroll")                                                      \
  for (int u = 0; u < 16; ++u) {                                         \
    float4 col = rr[u & 7];                                              \
    rr[u & 7] = (u < 8) ? pA[(u + 8) * 64 + lane]                        \
                        : pB[(u - 8) * 64 + lane];                       \
    float sh = dpp_shr1_negfill_f32(v3);                                 \
    float m0 = fmaxf(v0, sh);                                            \
    float m1 = fmaxf(v1, v0);                                            \
    float m2 = fmaxf(v2, v1);                                            \
    float m3 = fmaxf(v3, v2);                                            \
    w0 |= (__float_as_uint(v0 - m0) >> 31) << ((SHBASE) + u);            \
    w1 |= (__float_as_uint(v1 - m1) >> 31) << ((SHBASE) + u);            \
    w2 |= (__float_as_uint(v2 - m2) >> 31) << ((SHBASE) + u);            \
    w3 |= (__float_as_uint(v3 - m3) >> 31) << ((SHBASE) + u);            \
    v0 = col.x + m0;                                                     \
    v1 = col.y + m1;                                                     \
    v2 = col.z + m2;                                                     \
    v3 = col.w + m3;                                                     \
  }

__global__ __launch_bounds__(256, 1) void k_dp(
    const float* __restrict__ lpT, const int* __restrict__ xlp,
    const int* __restrict__ ylp, float* __restrict__ dr_out,
    int* __restrict__ cum_ws, int* __restrict__ xt_ws)
{
  const int b = blockIdx.x;
  const int tid = threadIdx.x;
  const int lane = tid & 63;
  const int w = tid >> 6;                 // 0 = consumer, 1..3 = producers
  __shared__ __align__(16) float    ring[6 * 16 * 256];  // 96 KB, 6 slots
  __shared__ __align__(16) uint32_t bits[8192];          // 32 KB
  __shared__ __align__(16) uint32_t dur[TX_];            // 1 KB
  __shared__ uint32_t flags[64];
  __shared__ int      prog;

  const float4* gb4   = (const float4*)(lpT + (size_t)b * TY_ * TX_);
  const float4* ring4 = (const float4*)ring;

  const int ylen = ylp[b];
  const int nch  = ((ylen + 31) >> 5) << 1;   // even # of 16-row chunks, 32..64

  if (tid < 64) flags[tid] = 0u;
  if (tid == 0) prog = -1;
  __syncthreads();

  if (w == 0) {
    // ---------------- consumer: pure LDS + VALU DP ----------------
    volatile uint32_t* vflag = flags;
    volatile int*      vprog = &prog;
    POLL_FLAG(0);
    float4 rr[8];
#pragma unroll
    for (int i = 0; i < 8; ++i) rr[i] = ring4[i * 64 + lane];  // slot0 rows 0..7

    float v0 = (lane == 0) ? 0.0f : NEGF;
    float v1 = NEGF, v2 = NEGF, v3 = NEGF;
    uint32_t w0 = 0, w1 = 0, w2 = 0, w3 = 0;
    int sA = 0, sB = 1;
    const float4* pA;
    const float4* pB;

    for (int cp = 0; cp < nch; cp += 2) {
      { int nf = (cp + 1 < nch) ? cp + 1 : nch - 1; POLL_FLAG(nf); }
      pA = ring4 + sA * 1024; pB = ring4 + sB * 1024;
      DP_CHUNK(0)
      asm volatile("" ::: "memory");
      *vprog = cp;
      sA = sB; sB = (sB == 5) ? 0 : sB + 1;

      { int nf = (cp + 2 < nch) ? cp + 2 : nch - 1; POLL_FLAG(nf); }
      pA = ring4 + sA * 1024; pB = ring4 + sB * 1024;
      DP_CHUNK(16)
      *(uint4*)&bits[(cp >> 1) * 256 + 4 * lane] = make_uint4(w0, w1, w2, w3);
      w0 = w1 = w2 = w3 = 0;
      asm volatile("" ::: "memory");
      *vprog = cp + 1;
      sA = sB; sB = (sB == 5) ? 0 : sB + 1;
    }
  } else {
    // ---------------- producers: global -> reg -> LDS ring ----------------
    const int p = w - 1;                  // 0..2, handles chunks c ≡ p (mod 3)
    volatile int*      vprog = &prog;
    volatile uint32_t* vflag = flags;
    for (int c = p; c < nch; c += 3) {
      const int need = c - 6;             // slot tenant c-6 must be consumed
      while (*vprog < need) __builtin_amdgcn_s_sleep(8);
      asm volatile("" ::: "memory");
      const float4* src = gb4 + (size_t)(c * 16) * 64 + lane;
      float4 tmp[16];
#pragma unroll
      for (int r = 0; r < 16; ++r) tmp[r] = src[r * 64];
      float4* dst = (float4*)&ring[(c % 6) * 4096] + lane;
#pragma unroll
      for (int r = 0; r < 16; ++r) dst[r * 64] = tmp[r];
      asm volatile("s_waitcnt lgkmcnt(0)" ::: "memory");
      vflag[c] = 1u;
    }
  }

  __syncthreads();
  dur[tid] = 0;
  __syncthreads();

  const int xlen = xlp[b];
  if (tid == 0) {
    int idx = xlen - 1;
    int t = ylen - 1;
    int cww = -2, cbase = -2;             // cached strip id
    uint4 strip = make_uint4(0u, 0u, 0u, 0u);
    while (t >= 0) {
      if (idx == 0) { dur[0] = (uint32_t)(t + 1); break; }
      int ww = t >> 5, rrm = t & 31;
      int base = idx & ~3;
      if (ww != cww || base != cbase) {
        strip = *(const uint4*)&bits[ww * 256 + base];
        cww = ww; cbase = base;
      }
      const int sel = idx & 3;
      uint32_t wd = (sel == 0) ? strip.x
                  : (sel == 1) ? strip.y
                  : (sel == 2) ? strip.z : strip.w;
      wd &= (rrm == 31) ? 0xffffffffu : ((1u << (rrm + 1)) - 1u);
      while (wd == 0 && ww > 0) {
        --ww;
        strip = *(const uint4*)&bits[ww * 256 + base];
        cww = ww;
        wd = (sel == 0) ? strip.x
           : (sel == 1) ? strip.y
           : (sel == 2) ? strip.z : strip.w;
      }
      if (wd == 0) { dur[idx] = (uint32_t)(t + 1); break; }
      int bitpos = 31 - __builtin_clz(wd);
      int tp = (ww << 5) | bitpos;       // step where diag fires -> decrement
      dur[idx] = (uint32_t)(t - tp + 1); // first visit of idx -> plain store
      --idx;
      t = tp - 1;
    }
  }
  __syncthreads();

  if (w == 0) {
    // wave-wide inclusive scan of durations -> cum, dr, and t->x scatter map
    uint32_t d0 = dur[4 * lane], d1 = dur[4 * lane + 1];
    uint32_t d2 = dur[4 * lane + 2], d3 = dur[4 * lane + 3];
    uint32_t own = d0 + d1 + d2 + d3;
    uint32_t s = own;
#pragma unroll
    for (int off = 1; off < 64; off <<= 1) {
      uint32_t n = __shfl_up(s, off);
      if (lane >= off) s += n;
    }
    uint32_t base = s - own;
    uint32_t c0 = base + d0, c1 = c0 + d1, c2 = c1 + d2, c3 = c2 + d3;
    int x = 4 * lane;
    cum_ws[b * TX_ + x]     = (int)c0;
    cum_ws[b * TX_ + x + 1] = (int)c1;
    cum_ws[b * TX_ + x + 2] = (int)c2;
    cum_ws[b * TX_ + x + 3] = (int)c3;
    dr_out[b * TX_ + x]     = (float)d0;
    dr_out[b * TX_ + x + 1] = (float)d1;
    dr_out[b * TX_ + x + 2] = (float)d2;
    dr_out[b * TX_ + x + 3] = (float)d3;
    int* xt = xt_ws + b * TY_;
    for (uint32_t t = c0 - d0; t < c0; ++t) xt[t] = x;
    for (uint32_t t = c1 - d1; t < c1; ++t) xt[t] = x + 1;
    for (uint32_t t = c2 - d2; t < c2; ++t) xt[t] = x + 2;
    for (uint32_t t = c3 - d3; t < c3; ++t) xt[t] = x + 3;
  }
}

// ---------------------------------------------------------------------------
// Kernel C (fused epilogue): blocks [0,TX) write attn rows from cum;
// blocks [TX,TX+H) gather o_en_ex[b,h,t] = t<ylen ? en[b,h,xt[b,t]] : 0.
// ---------------------------------------------------------------------------
__global__ __launch_bounds__(256) void k_epi(
    const int* __restrict__ cum_ws, const int* __restrict__ xt_ws,
    const float* __restrict__ en, const int* __restrict__ ylp,
    float* __restrict__ attn, float* __restrict__ oen)
{
  const int b = blockIdx.y, bx = blockIdx.x, tid = threadIdx.x;
  __shared__ float row[TX_];
  if (bx < TX_) {
    const int x = bx;
    int hi = cum_ws[b * TX_ + x];
    int lo = (x > 0) ? cum_ws[b * TX_ + x - 1] : 0;
    int t0 = tid * 4;
    float4 v;
    v.x = (t0     >= lo && t0     < hi) ? 1.f : 0.f;
    v.y = (t0 + 1 >= lo && t0 + 1 < hi) ? 1.f : 0.f;
    v.z = (t0 + 2 >= lo && t0 + 2 < hi) ? 1.f : 0.f;
    v.w = (t0 + 3 >= lo && t0 + 3 < hi) ? 1.f : 0.f;
    *(float4*)&attn[((size_t)(b * TX_ + x)) * TY_ + t0] = v;
  } else {
    const int h = bx - TX_;
    row[tid] = en[((size_t)(b * H_ + h)) * TX_ + tid];
    __syncthreads();
    const int ylen = ylp[b];
    int t0 = tid * 4;
    int4 xi = *(const int4*)&xt_ws[b * TY_ + t0];
    float4 v;
    v.x = (t0     < ylen) ? row[xi.x & (TX_ - 1)] : 0.f;
    v.y = (t0 + 1 < ylen) ? row[xi.y & (TX_ - 1)] : 0.f;
    v.z = (t0 + 2 < ylen) ? row[xi.z & (TX_ - 1)] : 0.f;
    v.w = (t0 + 3 < ylen) ? row[xi.w & (TX_ - 1)] : 0.f;
    *(float4*)&oen[((size_t)(b * H_ + h)) * TY_ + t0] = v;
  }
}

extern "C" void kernel_launch(void* const* d_in, const int* in_sizes, int n_in,
                              void* d_out, int out_size, void* d_ws, size_t ws_size,
                              hipStream_t stream)
{
  const float* en = (const float*)d_in[0];
  const float* mu = (const float*)d_in[1];
  const float* ls = (const float*)d_in[2];
  const float* y  = (const float*)d_in[3];
  const int*   xl = (const int*)d_in[4];
  const int*   yl = (const int*)d_in[5];

  float* out  = (float*)d_out;
  float* oen  = out;             // [B,H,TY]
  float* logp = out + OFF_LOGP;  // [B,TX,TY]
  float* attn = out + OFF_ATTN;  // [B,TX,TY] (doubles as lpT scratch first)
  float* dr   = out + OFF_DR;    // [B,TX]

  int* cum = (int*)d_ws;               // B*TX ints
  int* xt  = cum + B_ * TX_;           // B*TY ints

  k_logp<<<dim3(TX_ / 4, TY_ / 128, B_), 256, 0, stream>>>(mu, ls, y, xl, yl, logp, attn);
  k_dp  <<<B_,                           256, 0, stream>>>(attn, xl, yl, dr, cum, xt);
  k_epi <<<dim3(TX_ + H_, B_),           256, 0, stream>>>(cum, xt, en, yl, attn, oen);
}

// Round 8
// 166.395 us; speedup vs baseline: 1.0652x; 1.0652x over previous
//
#include <hip/hip_runtime.h>
#include <cstdint>
#include <cmath>

#define B_ 4
#define H_ 256
#define C_ 80
#define TX_ 256
#define TY_ 1024
#define NEGF (-1e9f)

// output layout (floats): o_en_ex [B,H,TY] | logp [B,TX,TY] | attn [B,TX,TY] | dr [B,TX]
#define OFF_LOGP (B_*H_*TY_)
#define OFF_ATTN (OFF_LOGP + B_*TX_*TY_)
#define OFF_DR   (OFF_ATTN + B_*TX_*TY_)

// __shfl_up(x,1) as pure VALU: DPP wave_shr:1 (ctrl 0x138); lane 0 gets NEGF.
__device__ __forceinline__ float dpp_shr1_negfill_f32(float x) {
  union { float f; int i; } u, o, r;
  u.f = x; o.f = NEGF;
  r.i = __builtin_amdgcn_update_dpp(o.i, u.i, 0x138, 0xf, 0xf, false);
  return r.f;
}

// ---------------------------------------------------------------------------
// Kernel A (R18 build, validated 166.7us): logp, 4 waves/SIMD, math
// BIT-IDENTICAL.  (R19's tq*8 split regressed ~5us -> stays reverted.)
// ---------------------------------------------------------------------------
__global__ __launch_bounds__(256) void k_logp(
    const float* __restrict__ mu, const float* __restrict__ ls,
    const float* __restrict__ y, const int* __restrict__ xlp,
    const int* __restrict__ ylp, float* __restrict__ logp_out,
    float* __restrict__ lpT)
{
  const int b  = blockIdx.z;
  const int tq = blockIdx.y;              // t-quarter: rows tq*256 .. tq*256+255
  const int x0 = blockIdx.x * 4;
  const int tid = threadIdx.x;
  const int lane = tid & 63;
  const int xi = tid >> 6;                // wave id == x-column index

  __shared__ double2 s_wm[4][C_];         // (w, -2*w*mu) packed -> ds_read_b128
  __shared__ double  s_wm2[4][C_];
  __shared__ double  s_lsv[4][C_];
  __shared__ double  s_K[4];
  __shared__ double  s_t0[4];
  __shared__ float   tile[256][4];        // [t_local][x] transpose staging

  for (int i = tid; i < 4 * C_; i += 256) {
    int xj = i / C_, c = i - xj * C_;
    double m = (double)mu[(b * C_ + c) * TX_ + x0 + xj];
    double l = (double)ls[(b * C_ + c) * TX_ + x0 + xj];
    double w = exp(-2.0 * l);
    s_wm[xj][c]  = make_double2(w, -2.0 * w * m);
    s_wm2[xj][c] = w * m * m;
    s_lsv[xj][c] = l;
  }
  __syncthreads();
  {
    int cc = lane;
    double kp = (cc < C_) ? s_wm2[xi][cc] : 0.0;
    double tp = (cc < C_) ? s_lsv[xi][cc] : 0.0;
    if (cc + 64 < C_) { kp += s_wm2[xi][cc + 64]; tp += s_lsv[xi][cc + 64]; }
#pragma unroll
    for (int off = 32; off; off >>= 1) {
      kp += __shfl_down(kp, off);
      tp += __shfl_down(tp, off);
    }
    if (cc == 0) { s_K[xi] = kp; s_t0[xi] = -0.5 * (tp * (1.0 / C_)); }
  }
  __syncthreads();

  // each thread: x = x0+xi, t = tq*256 + lane*4 .. +3
  double acc[4];
#pragma unroll
  for (int k = 0; k < 4; ++k) acc[k] = 0.0;

  const float4* yp = (const float4*)(y + (size_t)b * C_ * TY_ + tq * 256) + lane;
#pragma unroll 4
  for (int c = 0; c < C_; ++c) {
    float4 yv = yp[c * (TY_ / 4)];
    double y0 = yv.x, y1 = yv.y, y2 = yv.z, y3 = yv.w;
    double2 wm = s_wm[xi][c];
    double w = wm.x, m1 = wm.y;
    double u0 = fma(w, y0, m1), u1 = fma(w, y1, m1);
    double u2 = fma(w, y2, m1), u3 = fma(w, y3, m1);
    acc[0] = fma(u0, y0, acc[0]);
    acc[1] = fma(u1, y1, acc[1]);
    acc[2] = fma(u2, y2, acc[2]);
    acc[3] = fma(u3, y3, acc[3]);
  }

  const int xlen = xlp[b], ylen = ylp[b];
  const int x  = x0 + xi;
  const int t0 = tq * 256 + lane * 4;
  {
    double c0 = s_t0[xi], K = s_K[xi];
    float r[4];
#pragma unroll
    for (int k = 0; k < 4; ++k)
      r[k] = (float)((acc[k] + K) * (-0.5 / C_) + c0);
    *(float4*)&logp_out[((size_t)(b * TX_ + x)) * TY_ + t0] =
        make_float4(r[0], r[1], r[2], r[3]);
    bool xm = x < xlen;
#pragma unroll
    for (int k = 0; k < 4; ++k)
      tile[lane * 4 + k][xi] = (xm && (t0 + k) < ylen) ? r[k] : NEGF;
  }
  __syncthreads();

  // lpT[b][t][x0..x0+3] for t in this quarter; thread tid handles t_local=tid
  float* dst = lpT + (size_t)b * TY_ * TX_ + x0;
  const float4* tp = (const float4*)tile;
  *(float4*)&dst[(size_t)(tq * 256 + tid) * TX_] = tp[tid];
}

// ---------------------------------------------------------------------------
// Kernel B (R21): R16 forward (validated 79.6us) + REGISTER-BAND backtrack.
//
// R20 build break: __builtin_amdgcn_writelane doesn't exist -> dur[] stays
// in LDS (the store was never on the critical path).  The latency win is
// kept: the walk runs wave-uniform on wave 0 (full exec); the current
// 32-step band bits[ww][0..255] (1KB) is cached as a uint4 PER LANE (one
// ds_read_b128, reloaded only when ww changes, ~35x total); the word for
// column idx comes from __builtin_amdgcn_readlane (~5cyc) instead of a
// dependent ~120cyc LDS read.  dur[idx] written by lane 0 only (off-chain).
// Walk semantics verbatim from the passing R16 walk -> identical dur.
// ---------------------------------------------------------------------------
#define POLL_FLAG(i)                                                     \
  { while (vflag[i] == 0u) __builtin_amdgcn_s_sleep(1);                  \
    asm volatile("" ::: "memory"); }

#define DP_CHUNK(SHBASE)                                                 \
  _Pragma("unroll")                                                      \
  for (int u = 0; u < 16; ++u) {                                         \
    float4 col = rr[u & 7];                                              \
    rr[u & 7] = (u < 8) ? pA[(u + 8) * 64 + lane]                        \
                        : pB[(u - 8) * 64 + lane];                       \
    float sh = dpp_shr1_negfill_f32(v3);                                 \
    float m0 = fmaxf(v0, sh);                                            \
    float m1 = fmaxf(v1, v0);                                            \
    float m2 = fmaxf(v2, v1);                                            \
    float m3 = fmaxf(v3, v2);                                            \
    w0 |= (__float_as_uint(v0 - m0) >> 31) << ((SHBASE) + u);            \
    w1 |= (__float_as_uint(v1 - m1) >> 31) << ((SHBASE) + u);            \
    w2 |= (__float_as_uint(v2 - m2) >> 31) << ((SHBASE) + u);            \
    w3 |= (__float_as_uint(v3 - m3) >> 31) << ((SHBASE) + u);            \
    v0 = col.x + m0;                                                     \
    v1 = col.y + m1;                                                     \
    v2 = col.z + m2;                                                     \
    v3 = col.w + m3;                                                     \
  }

__global__ __launch_bounds__(256, 1) void k_dp(
    const float* __restrict__ lpT, const int* __restrict__ xlp,
    const int* __restrict__ ylp, float* __restrict__ dr_out,
    int* __restrict__ cum_ws, int* __restrict__ xt_ws)
{
  const int b = blockIdx.x;
  const int tid = threadIdx.x;
  const int lane = tid & 63;
  const int w = tid >> 6;                 // 0 = consumer, 1..3 = producers
  __shared__ __align__(16) float    ring[6 * 16 * 256];  // 96 KB, 6 slots
  __shared__ __align__(16) uint32_t bits[8192];          // 32 KB
  __shared__ __align__(16) uint32_t dur[TX_];            // 1 KB
  __shared__ uint32_t flags[64];
  __shared__ int      prog;

  const float4* gb4   = (const float4*)(lpT + (size_t)b * TY_ * TX_);
  const float4* ring4 = (const float4*)ring;

  const int ylen = ylp[b];
  const int nch  = ((ylen + 31) >> 5) << 1;   // even # of 16-row chunks, 32..64

  if (tid < 64) flags[tid] = 0u;
  if (tid == 0) prog = -1;
  __syncthreads();

  if (w == 0) {
    // ---------------- consumer: pure LDS + VALU DP ----------------
    volatile uint32_t* vflag = flags;
    volatile int*      vprog = &prog;
    POLL_FLAG(0);
    float4 rr[8];
#pragma unroll
    for (int i = 0; i < 8; ++i) rr[i] = ring4[i * 64 + lane];  // slot0 rows 0..7

    float v0 = (lane == 0) ? 0.0f : NEGF;
    float v1 = NEGF, v2 = NEGF, v3 = NEGF;
    uint32_t w0 = 0, w1 = 0, w2 = 0, w3 = 0;
    int sA = 0, sB = 1;
    const float4* pA;
    const float4* pB;

    for (int cp = 0; cp < nch; cp += 2) {
      { int nf = (cp + 1 < nch) ? cp + 1 : nch - 1; POLL_FLAG(nf); }
      pA = ring4 + sA * 1024; pB = ring4 + sB * 1024;
      DP_CHUNK(0)
      asm volatile("" ::: "memory");
      *vprog = cp;
      sA = sB; sB = (sB == 5) ? 0 : sB + 1;

      { int nf = (cp + 2 < nch) ? cp + 2 : nch - 1; POLL_FLAG(nf); }
      pA = ring4 + sA * 1024; pB = ring4 + sB * 1024;
      DP_CHUNK(16)
      *(uint4*)&bits[(cp >> 1) * 256 + 4 * lane] = make_uint4(w0, w1, w2, w3);
      w0 = w1 = w2 = w3 = 0;
      asm volatile("" ::: "memory");
      *vprog = cp + 1;
      sA = sB; sB = (sB == 5) ? 0 : sB + 1;
    }
  } else {
    // ---------------- producers: global -> reg -> LDS ring ----------------
    const int p = w - 1;                  // 0..2, handles chunks c ≡ p (mod 3)
    volatile int*      vprog = &prog;
    volatile uint32_t* vflag = flags;
    for (int c = p; c < nch; c += 3) {
      const int need = c - 6;             // slot tenant c-6 must be consumed
      while (*vprog < need) __builtin_amdgcn_s_sleep(8);
      asm volatile("" ::: "memory");
      const float4* src = gb4 + (size_t)(c * 16) * 64 + lane;
      float4 tmp[16];
#pragma unroll
      for (int r = 0; r < 16; ++r) tmp[r] = src[r * 64];
      float4* dst = (float4*)&ring[(c % 6) * 4096] + lane;
#pragma unroll
      for (int r = 0; r < 16; ++r) dst[r * 64] = tmp[r];
      asm volatile("s_waitcnt lgkmcnt(0)" ::: "memory");
      vflag[c] = 1u;
    }
  }

  __syncthreads();    // bits complete & visible; producers idle below
  dur[tid] = 0;
  __syncthreads();

  if (w == 0) {
    const int xlen = xlp[b];
    // ---- register-band backtrack (wave-uniform, full exec on wave 0) ----
    int idx = xlen - 1;
    int t = ylen - 1;
    int cww = -1;
    uint4 band = make_uint4(0u, 0u, 0u, 0u);
    while (t >= 0) {
      if (idx == 0) {
        if (lane == 0) dur[0] = (uint32_t)(t + 1);
        break;
      }
      int ww = t >> 5, rrm = t & 31;
      if (ww != cww) {
        band = *(const uint4*)&bits[ww * 256 + lane * 4];
        cww = ww;
      }
      const int src_lane = idx >> 2, sel = idx & 3;
      uint32_t bw = (sel == 0) ? band.x : (sel == 1) ? band.y
                  : (sel == 2) ? band.z : band.w;
      uint32_t wd = __builtin_amdgcn_readlane(bw, src_lane);
      wd &= (rrm == 31) ? 0xffffffffu : ((1u << (rrm + 1)) - 1u);
      while (wd == 0 && ww > 0) {
        --ww;
        band = *(const uint4*)&bits[ww * 256 + lane * 4];
        cww = ww;
        bw = (sel == 0) ? band.x : (sel == 1) ? band.y
           : (sel == 2) ? band.z : band.w;
        wd = __builtin_amdgcn_readlane(bw, src_lane);
      }
      if (wd == 0) {
        if (lane == 0) dur[idx] = (uint32_t)(t + 1);
        break;
      }
      int bitpos = 31 - __builtin_clz(wd);
      int tp = (ww << 5) | bitpos;       // step where diag fires -> decrement
      if (lane == 0) dur[idx] = (uint32_t)(t - tp + 1);
      --idx;
      t = tp - 1;
    }
  }
  __syncthreads();

  if (w == 0) {
    // wave-wide inclusive scan of durations -> cum, dr, and t->x scatter map
    uint32_t d0 = dur[4 * lane], d1 = dur[4 * lane + 1];
    uint32_t d2 = dur[4 * lane + 2], d3 = dur[4 * lane + 3];
    uint32_t own = d0 + d1 + d2 + d3;
    uint32_t s = own;
#pragma unroll
    for (int off = 1; off < 64; off <<= 1) {
      uint32_t n = __shfl_up(s, off);
      if (lane >= off) s += n;
    }
    uint32_t base = s - own;
    uint32_t c0 = base + d0, c1 = c0 + d1, c2 = c1 + d2, c3 = c2 + d3;
    int x = 4 * lane;
    cum_ws[b * TX_ + x]     = (int)c0;
    cum_ws[b * TX_ + x + 1] = (int)c1;
    cum_ws[b * TX_ + x + 2] = (int)c2;
    cum_ws[b * TX_ + x + 3] = (int)c3;
    dr_out[b * TX_ + x]     = (float)d0;
    dr_out[b * TX_ + x + 1] = (float)d1;
    dr_out[b * TX_ + x + 2] = (float)d2;
    dr_out[b * TX_ + x + 3] = (float)d3;
    int* xt = xt_ws + b * TY_;
    for (uint32_t t = c0 - d0; t < c0; ++t) xt[t] = x;
    for (uint32_t t = c1 - d1; t < c1; ++t) xt[t] = x + 1;
    for (uint32_t t = c2 - d2; t < c2; ++t) xt[t] = x + 2;
    for (uint32_t t = c3 - d3; t < c3; ++t) xt[t] = x + 3;
  }
}

// ---------------------------------------------------------------------------
// Kernel C (fused epilogue): blocks [0,TX) write attn rows from cum;
// blocks [TX,TX+H) gather o_en_ex[b,h,t] = t<ylen ? en[b,h,xt[b,t]] : 0.
// ---------------------------------------------------------------------------
__global__ __launch_bounds__(256) void k_epi(
    const int* __restrict__ cum_ws, const int* __restrict__ xt_ws,
    const float* __restrict__ en, const int* __restrict__ ylp,
    float* __restrict__ attn, float* __restrict__ oen)
{
  const int b = blockIdx.y, bx = blockIdx.x, tid = threadIdx.x;
  __shared__ float row[TX_];
  if (bx < TX_) {
    const int x = bx;
    int hi = cum_ws[b * TX_ + x];
    int lo = (x > 0) ? cum_ws[b * TX_ + x - 1] : 0;
    int t0 = tid * 4;
    float4 v;
    v.x = (t0     >= lo && t0     < hi) ? 1.f : 0.f;
    v.y = (t0 + 1 >= lo && t0 + 1 < hi) ? 1.f : 0.f;
    v.z = (t0 + 2 >= lo && t0 + 2 < hi) ? 1.f : 0.f;
    v.w = (t0 + 3 >= lo && t0 + 3 < hi) ? 1.f : 0.f;
    *(float4*)&attn[((size_t)(b * TX_ + x)) * TY_ + t0] = v;
  } else {
    const int h = bx - TX_;
    row[tid] = en[((size_t)(b * H_ + h)) * TX_ + tid];
    __syncthreads();
    const int ylen = ylp[b];
    int t0 = tid * 4;
    int4 xi = *(const int4*)&xt_ws[b * TY_ + t0];
    float4 v;
    v.x = (t0     < ylen) ? row[xi.x & (TX_ - 1)] : 0.f;
    v.y = (t0 + 1 < ylen) ? row[xi.y & (TX_ - 1)] : 0.f;
    v.z = (t0 + 2 < ylen) ? row[xi.z & (TX_ - 1)] : 0.f;
    v.w = (t0 + 3 < ylen) ? row[xi.w & (TX_ - 1)] : 0.f;
    *(float4*)&oen[((size_t)(b * H_ + h)) * TY_ + t0] = v;
  }
}

extern "C" void kernel_launch(void* const* d_in, const int* in_sizes, int n_in,
                              void* d_out, int out_size, void* d_ws, size_t ws_size,
                              hipStream_t stream)
{
  const float* en = (const float*)d_in[0];
  const float* mu = (const float*)d_in[1];
  const float* ls = (const float*)d_in[2];
  const float* y  = (const float*)d_in[3];
  const int*   xl = (const int*)d_in[4];
  const int*   yl = (const int*)d_in[5];

  float* out  = (float*)d_out;
  float* oen  = out;             // [B,H,TY]
  float* logp = out + OFF_LOGP;  // [B,TX,TY]
  float* attn = out + OFF_ATTN;  // [B,TX,TY] (doubles as lpT scratch first)
  float* dr   = out + OFF_DR;    // [B,TX]

  int* cum = (int*)d_ws;               // B*TX ints
  int* xt  = cum + B_ * TX_;           // B*TY ints

  k_logp<<<dim3(TX_ / 4, TY_ / 256, B_), 256, 0, stream>>>(mu, ls, y, xl, yl, logp, attn);
  k_dp  <<<B_,                           256, 0, stream>>>(attn, xl, yl, dr, cum, xt);
  k_epi <<<dim3(TX_ + H_, B_),           256, 0, stream>>>(cum, xt, en, yl, attn, oen);
}

// Round 9
// 165.106 us; speedup vs baseline: 1.0735x; 1.0078x over previous
//
#include <hip/hip_runtime.h>
#include <cstdint>
#include <cmath>

#define B_ 4
#define H_ 256
#define C_ 80
#define TX_ 256
#define TY_ 1024
#define NEGF (-1e9f)

// output layout (floats): o_en_ex [B,H,TY] | logp [B,TX,TY] | attn [B,TX,TY] | dr [B,TX]
#define OFF_LOGP (B_*H_*TY_)
#define OFF_ATTN (OFF_LOGP + B_*TX_*TY_)
#define OFF_DR   (OFF_ATTN + B_*TX_*TY_)

// ---------------------------------------------------------------------------
// Kernel A (R18 build, validated 166.7us): logp, 4 waves/SIMD, math
// BIT-IDENTICAL.
// ---------------------------------------------------------------------------
__global__ __launch_bounds__(256) void k_logp(
    const float* __restrict__ mu, const float* __restrict__ ls,
    const float* __restrict__ y, const int* __restrict__ xlp,
    const int* __restrict__ ylp, float* __restrict__ logp_out,
    float* __restrict__ lpT)
{
  const int b  = blockIdx.z;
  const int tq = blockIdx.y;              // t-quarter: rows tq*256 .. tq*256+255
  const int x0 = blockIdx.x * 4;
  const int tid = threadIdx.x;
  const int lane = tid & 63;
  const int xi = tid >> 6;                // wave id == x-column index

  __shared__ double2 s_wm[4][C_];         // (w, -2*w*mu) packed -> ds_read_b128
  __shared__ double  s_wm2[4][C_];
  __shared__ double  s_lsv[4][C_];
  __shared__ double  s_K[4];
  __shared__ double  s_t0[4];
  __shared__ float   tile[256][4];        // [t_local][x] transpose staging

  for (int i = tid; i < 4 * C_; i += 256) {
    int xj = i / C_, c = i - xj * C_;
    double m = (double)mu[(b * C_ + c) * TX_ + x0 + xj];
    double l = (double)ls[(b * C_ + c) * TX_ + x0 + xj];
    double w = exp(-2.0 * l);
    s_wm[xj][c]  = make_double2(w, -2.0 * w * m);
    s_wm2[xj][c] = w * m * m;
    s_lsv[xj][c] = l;
  }
  __syncthreads();
  {
    int cc = lane;
    double kp = (cc < C_) ? s_wm2[xi][cc] : 0.0;
    double tp = (cc < C_) ? s_lsv[xi][cc] : 0.0;
    if (cc + 64 < C_) { kp += s_wm2[xi][cc + 64]; tp += s_lsv[xi][cc + 64]; }
#pragma unroll
    for (int off = 32; off; off >>= 1) {
      kp += __shfl_down(kp, off);
      tp += __shfl_down(tp, off);
    }
    if (cc == 0) { s_K[xi] = kp; s_t0[xi] = -0.5 * (tp * (1.0 / C_)); }
  }
  __syncthreads();

  // each thread: x = x0+xi, t = tq*256 + lane*4 .. +3
  double acc[4];
#pragma unroll
  for (int k = 0; k < 4; ++k) acc[k] = 0.0;

  const float4* yp = (const float4*)(y + (size_t)b * C_ * TY_ + tq * 256) + lane;
#pragma unroll 4
  for (int c = 0; c < C_; ++c) {
    float4 yv = yp[c * (TY_ / 4)];
    double y0 = yv.x, y1 = yv.y, y2 = yv.z, y3 = yv.w;
    double2 wm = s_wm[xi][c];
    double w = wm.x, m1 = wm.y;
    double u0 = fma(w, y0, m1), u1 = fma(w, y1, m1);
    double u2 = fma(w, y2, m1), u3 = fma(w, y3, m1);
    acc[0] = fma(u0, y0, acc[0]);
    acc[1] = fma(u1, y1, acc[1]);
    acc[2] = fma(u2, y2, acc[2]);
    acc[3] = fma(u3, y3, acc[3]);
  }

  const int xlen = xlp[b], ylen = ylp[b];
  const int x  = x0 + xi;
  const int t0 = tq * 256 + lane * 4;
  {
    double c0 = s_t0[xi], K = s_K[xi];
    float r[4];
#pragma unroll
    for (int k = 0; k < 4; ++k)
      r[k] = (float)((acc[k] + K) * (-0.5 / C_) + c0);
    *(float4*)&logp_out[((size_t)(b * TX_ + x)) * TY_ + t0] =
        make_float4(r[0], r[1], r[2], r[3]);
    bool xm = x < xlen;
#pragma unroll
    for (int k = 0; k < 4; ++k)
      tile[lane * 4 + k][xi] = (xm && (t0 + k) < ylen) ? r[k] : NEGF;
  }
  __syncthreads();

  // lpT[b][t][x0..x0+3] for t in this quarter; thread tid handles t_local=tid
  float* dst = lpT + (size_t)b * TY_ * TX_ + x0;
  const float4* tp = (const float4*)tile;
  *(float4*)&dst[(size_t)(tq * 256 + tid) * TX_] = tp[tid];
}

// ---------------------------------------------------------------------------
// Kernel B (R22): R16 producer-consumer forward + consumer stall diet.
//
// R21 post-mortem: register-band backtrack was a null (79.6 -> 81.2) ->
// the forward loop is ~85-90% of k_dp; consumer stalls >50%.  Enumerable
// stalls removed this round:
//  (1) paired flag poll: ONE volatile ds_read_b64 covers 2 chunks (halves
//      both the dependent poll reads and the lgkmcnt drains they force);
//      nch is even so pair (cp+2,cp+3) is always valid when cp+2 < nch.
//  (2) persistent-NEGF DPP: sh feeds back as update_dpp's `old` operand --
//      lane 0 keeps NEGF forever, compiler drops the per-step v_mov fill.
//  (3) *vprog published once per 2 chunks (producer slack 6 -> >=5, still
//      deadlock-free; fewer ds_writes + scheduling barriers).
// Backtrack: reverted to the exact R16 LDS walk (known-good).
// Math bit-identical: same dpp ctrl 0x138, same compares, same bit layout.
// ---------------------------------------------------------------------------
#define POLL_PAIR(i)                                                     \
  { const volatile unsigned long long* vp2 =                             \
        (const volatile unsigned long long*)&flags[i];                   \
    for (;;) { unsigned long long fv = *vp2;                             \
      if ((unsigned)fv && (fv >> 32)) break;                             \
      __builtin_amdgcn_s_sleep(1); }                                     \
    asm volatile("" ::: "memory"); }

#define DP_CHUNK(SHBASE)                                                 \
  _Pragma("unroll")                                                      \
  for (int u = 0; u < 16; ++u) {                                         \
    float4 col = rr[u & 7];                                              \
    rr[u & 7] = (u < 8) ? pA[(u + 8) * 64 + lane]                        \
                        : pB[(u - 8) * 64 + lane];                       \
    sh_i = __builtin_amdgcn_update_dpp(sh_i, __float_as_int(v3),         \
                                       0x138, 0xf, 0xf, false);          \
    float sh = __int_as_float(sh_i);                                     \
    float m0 = fmaxf(v0, sh);                                            \
    float m1 = fmaxf(v1, v0);                                            \
    float m2 = fmaxf(v2, v1);                                            \
    float m3 = fmaxf(v3, v2);                                            \
    w0 |= (__float_as_uint(v0 - m0) >> 31) << ((SHBASE) + u);            \
    w1 |= (__float_as_uint(v1 - m1) >> 31) << ((SHBASE) + u);            \
    w2 |= (__float_as_uint(v2 - m2) >> 31) << ((SHBASE) + u);            \
    w3 |= (__float_as_uint(v3 - m3) >> 31) << ((SHBASE) + u);            \
    v0 = col.x + m0;                                                     \
    v1 = col.y + m1;                                                     \
    v2 = col.z + m2;                                                     \
    v3 = col.w + m3;                                                     \
  }

__global__ __launch_bounds__(256, 1) void k_dp(
    const float* __restrict__ lpT, const int* __restrict__ xlp,
    const int* __restrict__ ylp, float* __restrict__ dr_out,
    int* __restrict__ cum_ws, int* __restrict__ xt_ws)
{
  const int b = blockIdx.x;
  const int tid = threadIdx.x;
  const int lane = tid & 63;
  const int w = tid >> 6;                 // 0 = consumer, 1..3 = producers
  __shared__ __align__(16) float    ring[6 * 16 * 256];  // 96 KB, 6 slots
  __shared__ __align__(16) uint32_t bits[8192];          // 32 KB
  __shared__ __align__(16) uint32_t dur[TX_];            // 1 KB
  __shared__ __align__(16) uint32_t flags[64];
  __shared__ int      prog;

  const float4* gb4   = (const float4*)(lpT + (size_t)b * TY_ * TX_);
  const float4* ring4 = (const float4*)ring;

  const int ylen = ylp[b];
  const int nch  = ((ylen + 31) >> 5) << 1;   // even # of 16-row chunks, 32..64

  if (tid < 64) flags[tid] = 0u;
  if (tid == 0) prog = -1;
  __syncthreads();

  if (w == 0) {
    // ---------------- consumer: pure LDS + VALU DP ----------------
    volatile int* vprog = &prog;
    POLL_PAIR(0);                          // flags 0 and 1
    float4 rr[8];
#pragma unroll
    for (int i = 0; i < 8; ++i) rr[i] = ring4[i * 64 + lane];  // slot0 rows 0..7

    float v0 = (lane == 0) ? 0.0f : NEGF;
    float v1 = NEGF, v2 = NEGF, v3 = NEGF;
    uint32_t w0 = 0, w1 = 0, w2 = 0, w3 = 0;
    int sh_i = __float_as_int(NEGF);       // persistent; lane0 stays NEGF
    int sA = 0, sB = 1;
    const float4* pA;
    const float4* pB;

    for (int cp = 0; cp < nch; cp += 2) {
      if (cp + 2 < nch) POLL_PAIR(cp + 2); // readies cp+2 (this iter) & cp+3 (next)
      pA = ring4 + sA * 1024; pB = ring4 + sB * 1024;
      DP_CHUNK(0)
      sA = sB; sB = (sB == 5) ? 0 : sB + 1;

      pA = ring4 + sA * 1024; pB = ring4 + sB * 1024;
      DP_CHUNK(16)
      *(uint4*)&bits[(cp >> 1) * 256 + 4 * lane] = make_uint4(w0, w1, w2, w3);
      w0 = w1 = w2 = w3 = 0;
      asm volatile("" ::: "memory");
      *vprog = cp + 1;
      sA = sB; sB = (sB == 5) ? 0 : sB + 1;
    }
  } else {
    // ---------------- producers: global -> reg -> LDS ring ----------------
    const int p = w - 1;                  // 0..2, handles chunks c ≡ p (mod 3)
    volatile int*      vprog = &prog;
    volatile uint32_t* vflag = flags;
    for (int c = p; c < nch; c += 3) {
      const int need = c - 6;             // slot tenant c-6 must be consumed
      while (*vprog < need) __builtin_amdgcn_s_sleep(8);
      asm volatile("" ::: "memory");
      const float4* src = gb4 + (size_t)(c * 16) * 64 + lane;
      float4 tmp[16];
#pragma unroll
      for (int r = 0; r < 16; ++r) tmp[r] = src[r * 64];
      float4* dst = (float4*)&ring[(c % 6) * 4096] + lane;
#pragma unroll
      for (int r = 0; r < 16; ++r) dst[r * 64] = tmp[r];
      asm volatile("s_waitcnt lgkmcnt(0)" ::: "memory");
      vflag[c] = 1u;
    }
  }

  __syncthreads();
  dur[tid] = 0;
  __syncthreads();

  const int xlen = xlp[b];
  if (tid == 0) {
    int idx = xlen - 1;
    int t = ylen - 1;
    while (t >= 0) {
      if (idx == 0) { dur[0] = (uint32_t)(t + 1); break; }
      int ww = t >> 5, rrm = t & 31;
      uint32_t wd = bits[ww * 256 + idx];
      wd &= (rrm == 31) ? 0xffffffffu : ((1u << (rrm + 1)) - 1u);
      while (wd == 0 && ww > 0) { --ww; wd = bits[ww * 256 + idx]; }
      if (wd == 0) { dur[idx] = (uint32_t)(t + 1); break; }
      int bitpos = 31 - __builtin_clz(wd);
      int tp = (ww << 5) | bitpos;       // step where diag fires -> decrement
      dur[idx] = (uint32_t)(t - tp + 1); // first visit of idx -> plain store
      --idx;
      t = tp - 1;
    }
  }
  __syncthreads();

  if (w == 0) {
    // wave-wide inclusive scan of durations -> cum, dr, and t->x scatter map
    uint32_t d0 = dur[4 * lane], d1 = dur[4 * lane + 1];
    uint32_t d2 = dur[4 * lane + 2], d3 = dur[4 * lane + 3];
    uint32_t own = d0 + d1 + d2 + d3;
    uint32_t s = own;
#pragma unroll
    for (int off = 1; off < 64; off <<= 1) {
      uint32_t n = __shfl_up(s, off);
      if (lane >= off) s += n;
    }
    uint32_t base = s - own;
    uint32_t c0 = base + d0, c1 = c0 + d1, c2 = c1 + d2, c3 = c2 + d3;
    int x = 4 * lane;
    cum_ws[b * TX_ + x]     = (int)c0;
    cum_ws[b * TX_ + x + 1] = (int)c1;
    cum_ws[b * TX_ + x + 2] = (int)c2;
    cum_ws[b * TX_ + x + 3] = (int)c3;
    dr_out[b * TX_ + x]     = (float)d0;
    dr_out[b * TX_ + x + 1] = (float)d1;
    dr_out[b * TX_ + x + 2] = (float)d2;
    dr_out[b * TX_ + x + 3] = (float)d3;
    int* xt = xt_ws + b * TY_;
    for (uint32_t t = c0 - d0; t < c0; ++t) xt[t] = x;
    for (uint32_t t = c1 - d1; t < c1; ++t) xt[t] = x + 1;
    for (uint32_t t = c2 - d2; t < c2; ++t) xt[t] = x + 2;
    for (uint32_t t = c3 - d3; t < c3; ++t) xt[t] = x + 3;
  }
}

// ---------------------------------------------------------------------------
// Kernel C (fused epilogue): blocks [0,TX) write attn rows from cum;
// blocks [TX,TX+H) gather o_en_ex[b,h,t] = t<ylen ? en[b,h,xt[b,t]] : 0.
// ---------------------------------------------------------------------------
__global__ __launch_bounds__(256) void k_epi(
    const int* __restrict__ cum_ws, const int* __restrict__ xt_ws,
    const float* __restrict__ en, const int* __restrict__ ylp,
    float* __restrict__ attn, float* __restrict__ oen)
{
  const int b = blockIdx.y, bx = blockIdx.x, tid = threadIdx.x;
  __shared__ float row[TX_];
  if (bx < TX_) {
    const int x = bx;
    int hi = cum_ws[b * TX_ + x];
    int lo = (x > 0) ? cum_ws[b * TX_ + x - 1] : 0;
    int t0 = tid * 4;
    float4 v;
    v.x = (t0     >= lo && t0     < hi) ? 1.f : 0.f;
    v.y = (t0 + 1 >= lo && t0 + 1 < hi) ? 1.f : 0.f;
    v.z = (t0 + 2 >= lo && t0 + 2 < hi) ? 1.f : 0.f;
    v.w = (t0 + 3 >= lo && t0 + 3 < hi) ? 1.f : 0.f;
    *(float4*)&attn[((size_t)(b * TX_ + x)) * TY_ + t0] = v;
  } else {
    const int h = bx - TX_;
    row[tid] = en[((size_t)(b * H_ + h)) * TX_ + tid];
    __syncthreads();
    const int ylen = ylp[b];
    int t0 = tid * 4;
    int4 xi = *(const int4*)&xt_ws[b * TY_ + t0];
    float4 v;
    v.x = (t0     < ylen) ? row[xi.x & (TX_ - 1)] : 0.f;
    v.y = (t0 + 1 < ylen) ? row[xi.y & (TX_ - 1)] : 0.f;
    v.z = (t0 + 2 < ylen) ? row[xi.z & (TX_ - 1)] : 0.f;
    v.w = (t0 + 3 < ylen) ? row[xi.w & (TX_ - 1)] : 0.f;
    *(float4*)&oen[((size_t)(b * H_ + h)) * TY_ + t0] = v;
  }
}

extern "C" void kernel_launch(void* const* d_in, const int* in_sizes, int n_in,
                              void* d_out, int out_size, void* d_ws, size_t ws_size,
                              hipStream_t stream)
{
  const float* en = (const float*)d_in[0];
  const float* mu = (const float*)d_in[1];
  const float* ls = (const float*)d_in[2];
  const float* y  = (const float*)d_in[3];
  const int*   xl = (const int*)d_in[4];
  const int*   yl = (const int*)d_in[5];

  float* out  = (float*)d_out;
  float* oen  = out;             // [B,H,TY]
  float* logp = out + OFF_LOGP;  // [B,TX,TY]
  float* attn = out + OFF_ATTN;  // [B,TX,TY] (doubles as lpT scratch first)
  float* dr   = out + OFF_DR;    // [B,TX]

  int* cum = (int*)d_ws;               // B*TX ints
  int* xt  = cum + B_ * TX_;           // B*TY ints

  k_logp<<<dim3(TX_ / 4, TY_ / 256, B_), 256, 0, stream>>>(mu, ls, y, xl, yl, logp, attn);
  k_dp  <<<B_,                           256, 0, stream>>>(attn, xl, yl, dr, cum, xt);
  k_epi <<<dim3(TX_ + H_, B_),           256, 0, stream>>>(cum, xt, en, yl, attn, oen);
}

// Round 10
// 163.582 us; speedup vs baseline: 1.0835x; 1.0093x over previous
//
#include <hip/hip_runtime.h>
#include <cstdint>
#include <cmath>

#define B_ 4
#define H_ 256
#define C_ 80
#define TX_ 256
#define TY_ 1024
#define NEGF (-1e9f)

// output layout (floats): o_en_ex [B,H,TY] | logp [B,TX,TY] | attn [B,TX,TY] | dr [B,TX]
#define OFF_LOGP (B_*H_*TY_)
#define OFF_ATTN (OFF_LOGP + B_*TX_*TY_)
#define OFF_DR   (OFF_ATTN + B_*TX_*TY_)

// ---------------------------------------------------------------------------
// Kernel A (R18 build, validated): logp, 4 waves/SIMD, math BIT-IDENTICAL.
// ---------------------------------------------------------------------------
__global__ __launch_bounds__(256) void k_logp(
    const float* __restrict__ mu, const float* __restrict__ ls,
    const float* __restrict__ y, const int* __restrict__ xlp,
    const int* __restrict__ ylp, float* __restrict__ logp_out,
    float* __restrict__ lpT)
{
  const int b  = blockIdx.z;
  const int tq = blockIdx.y;              // t-quarter: rows tq*256 .. tq*256+255
  const int x0 = blockIdx.x * 4;
  const int tid = threadIdx.x;
  const int lane = tid & 63;
  const int xi = tid >> 6;                // wave id == x-column index

  __shared__ double2 s_wm[4][C_];         // (w, -2*w*mu) packed -> ds_read_b128
  __shared__ double  s_wm2[4][C_];
  __shared__ double  s_lsv[4][C_];
  __shared__ double  s_K[4];
  __shared__ double  s_t0[4];
  __shared__ float   tile[256][4];        // [t_local][x] transpose staging

  for (int i = tid; i < 4 * C_; i += 256) {
    int xj = i / C_, c = i - xj * C_;
    double m = (double)mu[(b * C_ + c) * TX_ + x0 + xj];
    double l = (double)ls[(b * C_ + c) * TX_ + x0 + xj];
    double w = exp(-2.0 * l);
    s_wm[xj][c]  = make_double2(w, -2.0 * w * m);
    s_wm2[xj][c] = w * m * m;
    s_lsv[xj][c] = l;
  }
  __syncthreads();
  {
    int cc = lane;
    double kp = (cc < C_) ? s_wm2[xi][cc] : 0.0;
    double tp = (cc < C_) ? s_lsv[xi][cc] : 0.0;
    if (cc + 64 < C_) { kp += s_wm2[xi][cc + 64]; tp += s_lsv[xi][cc + 64]; }
#pragma unroll
    for (int off = 32; off; off >>= 1) {
      kp += __shfl_down(kp, off);
      tp += __shfl_down(tp, off);
    }
    if (cc == 0) { s_K[xi] = kp; s_t0[xi] = -0.5 * (tp * (1.0 / C_)); }
  }
  __syncthreads();

  // each thread: x = x0+xi, t = tq*256 + lane*4 .. +3
  double acc[4];
#pragma unroll
  for (int k = 0; k < 4; ++k) acc[k] = 0.0;

  const float4* yp = (const float4*)(y + (size_t)b * C_ * TY_ + tq * 256) + lane;
#pragma unroll 4
  for (int c = 0; c < C_; ++c) {
    float4 yv = yp[c * (TY_ / 4)];
    double y0 = yv.x, y1 = yv.y, y2 = yv.z, y3 = yv.w;
    double2 wm = s_wm[xi][c];
    double w = wm.x, m1 = wm.y;
    double u0 = fma(w, y0, m1), u1 = fma(w, y1, m1);
    double u2 = fma(w, y2, m1), u3 = fma(w, y3, m1);
    acc[0] = fma(u0, y0, acc[0]);
    acc[1] = fma(u1, y1, acc[1]);
    acc[2] = fma(u2, y2, acc[2]);
    acc[3] = fma(u3, y3, acc[3]);
  }

  const int xlen = xlp[b], ylen = ylp[b];
  const int x  = x0 + xi;
  const int t0 = tq * 256 + lane * 4;
  {
    double c0 = s_t0[xi], K = s_K[xi];
    float r[4];
#pragma unroll
    for (int k = 0; k < 4; ++k)
      r[k] = (float)((acc[k] + K) * (-0.5 / C_) + c0);
    *(float4*)&logp_out[((size_t)(b * TX_ + x)) * TY_ + t0] =
        make_float4(r[0], r[1], r[2], r[3]);
    bool xm = x < xlen;
#pragma unroll
    for (int k = 0; k < 4; ++k)
      tile[lane * 4 + k][xi] = (xm && (t0 + k) < ylen) ? r[k] : NEGF;
  }
  __syncthreads();

  // lpT[b][t][x0..x0+3] for t in this quarter; thread tid handles t_local=tid
  float* dst = lpT + (size_t)b * TY_ * TX_ + x0;
  const float4* tp = (const float4*)tile;
  *(float4*)&dst[(size_t)(tq * 256 + tid) * TX_] = tp[tid];
}

// ---------------------------------------------------------------------------
// Kernel B (R23): producer-consumer forward with EXPLICIT two-bank register
// pipeline.
//
// R22 counter arithmetic: consumer SIMD ~38% VALU busy, ~115 cyc/step stall
// == one dependent LDS-read latency -> the per-step rotated rr[u&7] ring is
// being serialized by conservative compiler waitcnts.  Fix: two 8-row
// register banks; per 8-row group: burst-issue 8 ds_read_b128 for group G+1
// into the back bank, then consume group G from the front bank (issued a
// full group ~400cyc earlier).  One lgkm wait per 8 steps, none per-step.
// Poll/publish cadence identical to R22 (pair-poll per 32 steps, vprog per
// 2 chunks; chunk cp+2's slot is only touched after POLL_PAIR(cp+2)).
// Bitpack: w = (w>>1) | (sign&0x80000000) -- 3 ops/reg; after exactly 32
// steps bit of step u sits at position u -> bits[] layout BIT-IDENTICAL.
// Backtrack/scan/scatter verbatim from the passing R22 build.
// ---------------------------------------------------------------------------
#define POLL_PAIR(i)                                                     \
  { const volatile unsigned long long* vp2 =                             \
        (const volatile unsigned long long*)&flags[i];                   \
    for (;;) { unsigned long long fv = *vp2;                             \
      if ((unsigned)fv && (fv >> 32)) break;                             \
      __builtin_amdgcn_s_sleep(1); }                                     \
    asm volatile("" ::: "memory"); }

#define ISSUE8(BANK, SC, HALF)                                           \
  _Pragma("unroll")                                                      \
  for (int i = 0; i < 8; ++i)                                            \
    BANK[i] = ring4[(SC) * 1024 + ((HALF) * 8 + i) * 64 + lane];

#define CONS8(BANK)                                                      \
  _Pragma("unroll")                                                      \
  for (int u = 0; u < 8; ++u) {                                          \
    float4 col = BANK[u];                                                \
    sh_i = __builtin_amdgcn_update_dpp(sh_i, __float_as_int(v3),         \
                                       0x138, 0xf, 0xf, false);          \
    float sh = __int_as_float(sh_i);                                     \
    float m0 = fmaxf(v0, sh);                                            \
    float m1 = fmaxf(v1, v0);                                            \
    float m2 = fmaxf(v2, v1);                                            \
    float m3 = fmaxf(v3, v2);                                            \
    w0 = (w0 >> 1) | (__float_as_uint(v0 - m0) & 0x80000000u);           \
    w1 = (w1 >> 1) | (__float_as_uint(v1 - m1) & 0x80000000u);           \
    w2 = (w2 >> 1) | (__float_as_uint(v2 - m2) & 0x80000000u);           \
    w3 = (w3 >> 1) | (__float_as_uint(v3 - m3) & 0x80000000u);           \
    v0 = col.x + m0;                                                     \
    v1 = col.y + m1;                                                     \
    v2 = col.z + m2;                                                     \
    v3 = col.w + m3;                                                     \
  }

__global__ __launch_bounds__(256, 1) void k_dp(
    const float* __restrict__ lpT, const int* __restrict__ xlp,
    const int* __restrict__ ylp, float* __restrict__ dr_out,
    int* __restrict__ cum_ws, int* __restrict__ xt_ws)
{
  const int b = blockIdx.x;
  const int tid = threadIdx.x;
  const int lane = tid & 63;
  const int w = tid >> 6;                 // 0 = consumer, 1..3 = producers
  __shared__ __align__(16) float    ring[6 * 16 * 256];  // 96 KB, 6 slots
  __shared__ __align__(16) uint32_t bits[8192];          // 32 KB
  __shared__ __align__(16) uint32_t dur[TX_];            // 1 KB
  __shared__ __align__(16) uint32_t flags[64];
  __shared__ int      prog;

  const float4* gb4   = (const float4*)(lpT + (size_t)b * TY_ * TX_);
  const float4* ring4 = (const float4*)ring;

  const int ylen = ylp[b];
  const int nch  = ((ylen + 31) >> 5) << 1;   // even # of 16-row chunks, 32..64

  if (tid < 64) flags[tid] = 0u;
  if (tid == 0) prog = -1;
  __syncthreads();

  if (w == 0) {
    // ---------------- consumer: pure LDS + VALU DP ----------------
    volatile int* vprog = &prog;
    POLL_PAIR(0);                          // chunks 0 and 1 staged
    float4 rrA[8], rrB[8];

    float v0 = (lane == 0) ? 0.0f : NEGF;
    float v1 = NEGF, v2 = NEGF, v3 = NEGF;
    uint32_t w0 = 0, w1 = 0, w2 = 0, w3 = 0;
    int sh_i = __float_as_int(NEGF);       // persistent; lane0 stays NEGF
    int slot = 0;

    ISSUE8(rrA, 0, 0);                     // group 0 (chunk 0, rows 0..7)

    for (int cp = 0; cp < nch; cp += 2) {
      if (cp + 2 < nch) POLL_PAIR(cp + 2); // flags cp+2 & cp+3
      const int s0 = slot;
      const int s1 = (s0 + 1 == 6) ? 0 : s0 + 1;
      const int s2 = (s1 + 1 == 6) ? 0 : s1 + 1;

      ISSUE8(rrB, s0, 1)                   // group 4k+1
      CONS8(rrA)                           // group 4k   (bits 0..7)
      ISSUE8(rrA, s1, 0)                   // group 4k+2
      CONS8(rrB)                           // group 4k+1 (bits 8..15)
      ISSUE8(rrB, s1, 1)                   // group 4k+3
      CONS8(rrA)                           // group 4k+2 (bits 16..23)
      if (cp + 2 < nch) { ISSUE8(rrA, s2, 0) }  // group 4k+4 (next iter)
      CONS8(rrB)                           // group 4k+3 (bits 24..31)

      *(uint4*)&bits[(cp >> 1) * 256 + 4 * lane] = make_uint4(w0, w1, w2, w3);
      w0 = w1 = w2 = w3 = 0;
      asm volatile("" ::: "memory");
      *vprog = cp + 1;
      slot = s2;
    }
  } else {
    // ---------------- producers: global -> reg -> LDS ring ----------------
    const int p = w - 1;                  // 0..2, handles chunks c ≡ p (mod 3)
    volatile int*      vprog = &prog;
    volatile uint32_t* vflag = flags;
    for (int c = p; c < nch; c += 3) {
      const int need = c - 6;             // slot tenant c-6 must be consumed
      while (*vprog < need) __builtin_amdgcn_s_sleep(8);
      asm volatile("" ::: "memory");
      const float4* src = gb4 + (size_t)(c * 16) * 64 + lane;
      float4 tmp[16];
#pragma unroll
      for (int r = 0; r < 16; ++r) tmp[r] = src[r * 64];
      float4* dst = (float4*)&ring[(c % 6) * 4096] + lane;
#pragma unroll
      for (int r = 0; r < 16; ++r) dst[r * 64] = tmp[r];
      asm volatile("s_waitcnt lgkmcnt(0)" ::: "memory");
      vflag[c] = 1u;
    }
  }

  __syncthreads();
  dur[tid] = 0;
  __syncthreads();

  const int xlen = xlp[b];
  if (tid == 0) {
    int idx = xlen - 1;
    int t = ylen - 1;
    while (t >= 0) {
      if (idx == 0) { dur[0] = (uint32_t)(t + 1); break; }
      int ww = t >> 5, rrm = t & 31;
      uint32_t wd = bits[ww * 256 + idx];
      wd &= (rrm == 31) ? 0xffffffffu : ((1u << (rrm + 1)) - 1u);
      while (wd == 0 && ww > 0) { --ww; wd = bits[ww * 256 + idx]; }
      if (wd == 0) { dur[idx] = (uint32_t)(t + 1); break; }
      int bitpos = 31 - __builtin_clz(wd);
      int tp = (ww << 5) | bitpos;       // step where diag fires -> decrement
      dur[idx] = (uint32_t)(t - tp + 1); // first visit of idx -> plain store
      --idx;
      t = tp - 1;
    }
  }
  __syncthreads();

  if (w == 0) {
    // wave-wide inclusive scan of durations -> cum, dr, and t->x scatter map
    uint32_t d0 = dur[4 * lane], d1 = dur[4 * lane + 1];
    uint32_t d2 = dur[4 * lane + 2], d3 = dur[4 * lane + 3];
    uint32_t own = d0 + d1 + d2 + d3;
    uint32_t s = own;
#pragma unroll
    for (int off = 1; off < 64; off <<= 1) {
      uint32_t n = __shfl_up(s, off);
      if (lane >= off) s += n;
    }
    uint32_t base = s - own;
    uint32_t c0 = base + d0, c1 = c0 + d1, c2 = c1 + d2, c3 = c2 + d3;
    int x = 4 * lane;
    cum_ws[b * TX_ + x]     = (int)c0;
    cum_ws[b * TX_ + x + 1] = (int)c1;
    cum_ws[b * TX_ + x + 2] = (int)c2;
    cum_ws[b * TX_ + x + 3] = (int)c3;
    dr_out[b * TX_ + x]     = (float)d0;
    dr_out[b * TX_ + x + 1] = (float)d1;
    dr_out[b * TX_ + x + 2] = (float)d2;
    dr_out[b * TX_ + x + 3] = (float)d3;
    int* xt = xt_ws + b * TY_;
    for (uint32_t t = c0 - d0; t < c0; ++t) xt[t] = x;
    for (uint32_t t = c1 - d1; t < c1; ++t) xt[t] = x + 1;
    for (uint32_t t = c2 - d2; t < c2; ++t) xt[t] = x + 2;
    for (uint32_t t = c3 - d3; t < c3; ++t) xt[t] = x + 3;
  }
}

// ---------------------------------------------------------------------------
// Kernel C (fused epilogue): blocks [0,TX) write attn rows from cum;
// blocks [TX,TX+H) gather o_en_ex[b,h,t] = t<ylen ? en[b,h,xt[b,t]] : 0.
// ---------------------------------------------------------------------------
__global__ __launch_bounds__(256) void k_epi(
    const int* __restrict__ cum_ws, const int* __restrict__ xt_ws,
    const float* __restrict__ en, const int* __restrict__ ylp,
    float* __restrict__ attn, float* __restrict__ oen)
{
  const int b = blockIdx.y, bx = blockIdx.x, tid = threadIdx.x;
  __shared__ float row[TX_];
  if (bx < TX_) {
    const int x = bx;
    int hi = cum_ws[b * TX_ + x];
    int lo = (x > 0) ? cum_ws[b * TX_ + x - 1] : 0;
    int t0 = tid * 4;
    float4 v;
    v.x = (t0     >= lo && t0     < hi) ? 1.f : 0.f;
    v.y = (t0 + 1 >= lo && t0 + 1 < hi) ? 1.f : 0.f;
    v.z = (t0 + 2 >= lo && t0 + 2 < hi) ? 1.f : 0.f;
    v.w = (t0 + 3 >= lo && t0 + 3 < hi) ? 1.f : 0.f;
    *(float4*)&attn[((size_t)(b * TX_ + x)) * TY_ + t0] = v;
  } else {
    const int h = bx - TX_;
    row[tid] = en[((size_t)(b * H_ + h)) * TX_ + tid];
    __syncthreads();
    const int ylen = ylp[b];
    int t0 = tid * 4;
    int4 xi = *(const int4*)&xt_ws[b * TY_ + t0];
    float4 v;
    v.x = (t0     < ylen) ? row[xi.x & (TX_ - 1)] : 0.f;
    v.y = (t0 + 1 < ylen) ? row[xi.y & (TX_ - 1)] : 0.f;
    v.z = (t0 + 2 < ylen) ? row[xi.z & (TX_ - 1)] : 0.f;
    v.w = (t0 + 3 < ylen) ? row[xi.w & (TX_ - 1)] : 0.f;
    *(float4*)&oen[((size_t)(b * H_ + h)) * TY_ + t0] = v;
  }
}

extern "C" void kernel_launch(void* const* d_in, const int* in_sizes, int n_in,
                              void* d_out, int out_size, void* d_ws, size_t ws_size,
                              hipStream_t stream)
{
  const float* en = (const float*)d_in[0];
  const float* mu = (const float*)d_in[1];
  const float* ls = (const float*)d_in[2];
  const float* y  = (const float*)d_in[3];
  const int*   xl = (const int*)d_in[4];
  const int*   yl = (const int*)d_in[5];

  float* out  = (float*)d_out;
  float* oen  = out;             // [B,H,TY]
  float* logp = out + OFF_LOGP;  // [B,TX,TY]
  float* attn = out + OFF_ATTN;  // [B,TX,TY] (doubles as lpT scratch first)
  float* dr   = out + OFF_DR;    // [B,TX]

  int* cum = (int*)d_ws;               // B*TX ints
  int* xt  = cum + B_ * TX_;           // B*TY ints

  k_logp<<<dim3(TX_ / 4, TY_ / 256, B_), 256, 0, stream>>>(mu, ls, y, xl, yl, logp, attn);
  k_dp  <<<B_,                           256, 0, stream>>>(attn, xl, yl, dr, cum, xt);
  k_epi <<<dim3(TX_ + H_, B_),           256, 0, stream>>>(cum, xt, en, yl, attn, oen);
}